// Round 7
// baseline (1451.805 us; speedup 1.0000x reference)
//
#include <hip/hip_runtime.h>

// ---------------------------------------------------------------------------
// H2Q knot kernel: embed -> 8 doubling quaternion expansion steps ->
// 6 quaternion-linear+normalize layers -> vocab head (+ stability loss).
// R7 = R6 with the LDS double-buffer sized correctly: BK=64 needs
// 128x64 = 16KB per buffer (R6 declared 8KB -> H sub-tile aliased the other
// buffer + overran the array; absmax 3.2). Structure:
//  - W fragments load directly global->VGPR (L2-resident after XCD swizzle).
//  - Act LDS double-buffered, ONE barrier per BK=64 iter; staging issued
//    right after the barrier, consumed one full MFMA block later.
//  - K is a template parameter: full unroll, immediate-offset addressing.
//  - XCD swizzle: xcd=L%8 owns token-tiles [32*xcd,32*xcd+32), n fastest.
// ---------------------------------------------------------------------------

typedef _Float16 f16x8 __attribute__((ext_vector_type(8)));
typedef float    f32x4 __attribute__((ext_vector_type(4)));

#define GL2LDS16(gp, lp) __builtin_amdgcn_global_load_lds(                     \
    (const __attribute__((address_space(1))) void*)(gp),                       \
    (__attribute__((address_space(3))) void*)(lp), 16, 0, 0)

__device__ __forceinline__ unsigned short f2h(float f) {
  union { _Float16 h; unsigned short u; } c;
  c.h = (_Float16)f;                       // RNE
  return c.u;
}
__device__ __forceinline__ float h2f(unsigned short u) {
  union { unsigned short u; _Float16 h; } c;
  c.u = u;
  return (float)c.h;
}

// ---------------------------------------------------------------------------
// Fused weight prep: all Hamilton expansions + head conversion in ONE kernel.
// Hamilton block (E[n][k], n=4o+a, k=4i+b):
//  a=0: [ Wr,-Wi,-Wj,-Wk]  a=1: [ Wi, Wr, Wk,-Wj]
//  a=2: [ Wj,-Wk, Wr, Wi]  a=3: [ Wk, Wj,-Wi, Wr]
// ---------------------------------------------------------------------------
__device__ __forceinline__ void expand_one(const float* __restrict__ w,
                                           unsigned short* __restrict__ out,
                                           int cq, int kbits, int id) {
  const int K = 1 << kbits;
  const int n = id >> kbits;
  const int k = id & (K - 1);
  float val = 0.f;
  if (n < 4 * cq) {
    const int o = n >> 2, a = n & 3, i = k >> 2, b = k & 3;
    const int   comp[4][4] = {{0,1,2,3},{1,0,3,2},{2,3,0,1},{3,2,1,0}};
    const float sgn [4][4] = {{1.f,-1.f,-1.f,-1.f},{1.f,1.f,1.f,-1.f},
                              {1.f,-1.f,1.f,1.f},{1.f,1.f,-1.f,1.f}};
    val = sgn[a][b] * w[comp[a][b] * cq * cq + o * cq + i];
  }
  out[id] = f2h(val);
}

__global__ __launch_bounds__(256) void prep_weights(
    const float* __restrict__ we4, const float* __restrict__ we5,
    const float* __restrict__ we6, const float* __restrict__ we7,
    const float* __restrict__ wlay, const float* __restrict__ wh,
    unsigned short* __restrict__ E4, unsigned short* __restrict__ E5,
    unsigned short* __restrict__ E6, unsigned short* __restrict__ E7,
    unsigned short* __restrict__ EL, unsigned short* __restrict__ WH) {
  const int b = blockIdx.x;
  const int tid = threadIdx.x;
  if (b < 32) {
    expand_one(we4, E4, 16, 6, b * 256 + tid);
  } else if (b < 96) {
    expand_one(we5, E5, 32, 7, (b - 32) * 256 + tid);
  } else if (b < 352) {
    expand_one(we6, E6, 64, 8, (b - 96) * 256 + tid);
  } else if (b < 1376) {
    expand_one(we7, E7, 128, 9, (b - 352) * 256 + tid);
  } else if (b < 25952) {
    const int d = (b - 1376) >> 12;               // 4096 blocks per layer
    const int id = ((b - 1376) & 4095) * 256 + tid;
    expand_one(wlay + (size_t)d * 262144, EL + (size_t)d * 1048576, 256, 10,
               id);
  } else {
    const int id = (b - 25952) * 256 + tid;       // 393216 head elements
    const int v = id >> 10, k = id & 1023;
    WH[id] = f2h(v < 257 ? wh[v * 1024 + k] : 0.f);
  }
}

// ---------------------------------------------------------------------------
// Embed + expansion steps 0..3 (cq=1,2,4,8), one token per thread (weights are
// wave-uniform -> scalar-cached broadcast loads). Output: fp16 [32768][64].
// ---------------------------------------------------------------------------
template <int CQ>
__device__ __forceinline__ void exp_step(float (&q)[16][4],
                                         const float* __restrict__ w) {
  float d[CQ][4];
#pragma unroll
  for (int o = 0; o < CQ; o++) {
    float pr = 0.f, pi = 0.f, pj = 0.f, pk = 0.f;
#pragma unroll
    for (int i = 0; i < CQ; i++) {
      const float wr = w[0 * CQ * CQ + o * CQ + i];
      const float wi = w[1 * CQ * CQ + o * CQ + i];
      const float wj = w[2 * CQ * CQ + o * CQ + i];
      const float wk = w[3 * CQ * CQ + o * CQ + i];
      const float qr = q[i][0], qi = q[i][1], qj = q[i][2], qk = q[i][3];
      pr += wr * qr - wi * qi - wj * qj - wk * qk;
      pi += wi * qr + wr * qi + wk * qj - wj * qk;
      pj += wj * qr - wk * qi + wr * qj + wi * qk;
      pk += wk * qr + wj * qi - wi * qj + wr * qk;
    }
    d[o][0] = tanhf(pr); d[o][1] = tanhf(pi);
    d[o][2] = tanhf(pj); d[o][3] = tanhf(pk);
  }
#pragma unroll
  for (int o = 0; o < CQ; o++)
#pragma unroll
    for (int a = 0; a < 4; a++) {
      const float dd = d[o][a], qq = q[o][a];
      q[o][a]      = qq + dd;
      q[CQ + o][a] = qq - dd;
    }
}

__global__ __launch_bounds__(256) void embed_expand(
    const int* __restrict__ x, const float* __restrict__ emb,
    const float* __restrict__ w0, const float* __restrict__ w1,
    const float* __restrict__ w2, const float* __restrict__ w3,
    unsigned short* __restrict__ out) {
  const int t = blockIdx.x * 256 + threadIdx.x;  // 32768 tokens
  float q[16][4];
  const int v = x[t];
  const float4 e = *(const float4*)(emb + v * 4);
  q[0][0] = e.x; q[0][1] = e.y; q[0][2] = e.z; q[0][3] = e.w;
  exp_step<1>(q, w0);
  exp_step<2>(q, w1);
  exp_step<4>(q, w2);
  exp_step<8>(q, w3);
  ushort4* o4 = (ushort4*)(out + (size_t)t * 64);
#pragma unroll
  for (int c = 0; c < 16; c++) {
    ushort4 u;
    u.x = f2h(q[c][0]); u.y = f2h(q[c][1]);
    u.z = f2h(q[c][2]); u.w = f2h(q[c][3]);
    o4[c] = u;
  }
}

// ---------------------------------------------------------------------------
// Fused GEMM: D[n][token] = sum_k W[n][k] * Act[token][k] (fp16, k-contig).
// Grid (Gx = #n-tiles, 256 token-tiles) with XCD swizzle. 128x128 block
// tile, 4 waves each 64x64 (4x4 of 16x16x32 MFMA, A=W, B=Act).
// C/D: col=token=lane&15, row=n=(lane>>4)*4+reg -> lane owns a quaternion.
// K-loop (BK=64, K template, fully unrolled): Act double-buffered in LDS
// (16KB/buffer: [0,4096) = k-slice L, [4096,8192) = k-slice H), one
// barrier/iter; W per-lane direct global loads prefetched one iter ahead.
// EPI: 0 = expansion (delta=tanh, write q+delta | q-delta, width 2*Nreal)
//      1 = quaternion normalize -> fp16 [token][1024]
//      2 = EPI1 + stability-loss accumulation (mean |r|)
//      3 = head: fp32 store to d_out[token*257 + n], n < 257
// ---------------------------------------------------------------------------
template <int EPI, int K>
__global__ __launch_bounds__(256) void gemm_epi(
    const unsigned short* __restrict__ W,
    const unsigned short* __restrict__ Act,
    unsigned short* __restrict__ OutB, float* __restrict__ OutF,
    int Nreal, int ldout) {
  __shared__ unsigned short At[2][128 * 64];   // 16KB per buffer (BK=64)
  __shared__ float lsum[4];

  const int tid  = threadIdx.x;
  const int wave = tid >> 6;
  const int lane = tid & 63;
  const int l15  = lane & 15;
  const int quad = lane >> 4;

  const int Gx = gridDim.x;
  const int L  = blockIdx.y * Gx + blockIdx.x;
  const int j  = L & 7;
  const int s  = L >> 3;
  const int nblock = (s % Gx) * 128;               // n (output feature)
  const int mblock = (32 * j + s / Gx) * 128;      // token
  const int wn = (wave & 1) * 64;
  const int wm = (wave >> 1) * 64;

  f32x4 acc[4][4];
  const f32x4 zero = {0.f, 0.f, 0.f, 0.f};
#pragma unroll
  for (int a = 0; a < 4; a++)
#pragma unroll
    for (int b = 0; b < 4; b++) acc[a][b] = zero;

  // Act staging: row = tid>>2 (64 rows/call), sub = tid&3 (16B slice of row)
  const int row0 = tid >> 2;
  const int sub  = tid & 3;
  const unsigned short* gA0 = Act + (size_t)(mblock + row0)      * K + sub * 8;
  const unsigned short* gA1 = Act + (size_t)(mblock + row0 + 64) * K + sub * 8;

  // W per-lane fragment base addresses (A-operand: row=l15, k=quad*8+j)
  const unsigned short* gw[4];
#pragma unroll
  for (int tn = 0; tn < 4; tn++)
    gw[tn] = W + (size_t)(nblock + wn + tn * 16 + l15) * K + quad * 8;

  constexpr int NIT = K / 64;

  // prologue: stage iter 0 into buffer 0; load W regs for iter 0
  GL2LDS16(gA0,      &At[0][wave * 512]);
  GL2LDS16(gA1,      &At[0][2048 + wave * 512]);
  GL2LDS16(gA0 + 32, &At[0][4096 + wave * 512]);
  GL2LDS16(gA1 + 32, &At[0][4096 + 2048 + wave * 512]);
  f16x8 wfrL[4], wfrH[4];
#pragma unroll
  for (int tn = 0; tn < 4; tn++) {
    wfrL[tn] = *(const f16x8*)(gw[tn]);
    wfrH[tn] = *(const f16x8*)(gw[tn] + 32);
  }

#pragma unroll
  for (int it = 0; it < NIT; it++) {
    const int kb = it * 64;
    const int cur = it & 1, nxt = cur ^ 1;
    __syncthreads();                       // buffer `cur` (iter it) ready
    // stage iter it+1 into `nxt` -- consumed one barrier later, so the
    // vmcnt drain at the next barrier is covered by this iter's MFMAs
    if (it + 1 < NIT) {
      GL2LDS16(gA0 + kb + 64, &At[nxt][wave * 512]);
      GL2LDS16(gA1 + kb + 64, &At[nxt][2048 + wave * 512]);
      GL2LDS16(gA0 + kb + 96, &At[nxt][4096 + wave * 512]);
      GL2LDS16(gA1 + kb + 96, &At[nxt][4096 + 2048 + wave * 512]);
    }
    // Act fragments from LDS (B-operand)
    f16x8 bfrL[4], bfrH[4];
#pragma unroll
    for (int tm = 0; tm < 4; tm++) {
      bfrL[tm] = *(const f16x8*)&At[cur][(wm + tm * 16 + l15) * 32 + quad * 8];
      bfrH[tm] =
          *(const f16x8*)&At[cur][4096 + (wm + tm * 16 + l15) * 32 + quad * 8];
    }
    // prefetch next W fragments (registers; independent of the barrier)
    f16x8 wfrLn[4], wfrHn[4];
    if (it + 1 < NIT) {
#pragma unroll
      for (int tn = 0; tn < 4; tn++) {
        wfrLn[tn] = *(const f16x8*)(gw[tn] + kb + 64);
        wfrHn[tn] = *(const f16x8*)(gw[tn] + kb + 96);
      }
    }
#pragma unroll
    for (int tn = 0; tn < 4; tn++)
#pragma unroll
      for (int tm = 0; tm < 4; tm++)
        acc[tn][tm] = __builtin_amdgcn_mfma_f32_16x16x32_f16(
            wfrL[tn], bfrL[tm], acc[tn][tm], 0, 0, 0);
#pragma unroll
    for (int tn = 0; tn < 4; tn++)
#pragma unroll
      for (int tm = 0; tm < 4; tm++)
        acc[tn][tm] = __builtin_amdgcn_mfma_f32_16x16x32_f16(
            wfrH[tn], bfrH[tm], acc[tn][tm], 0, 0, 0);
    if (it + 1 < NIT) {
#pragma unroll
      for (int tn = 0; tn < 4; tn++) {
        wfrL[tn] = wfrLn[tn];
        wfrH[tn] = wfrHn[tn];
      }
    }
  }

  if constexpr (EPI == 0) {
#pragma unroll
    for (int tn = 0; tn < 4; tn++) {
      const int n = nblock + wn + tn * 16 + quad * 4;
      if (n < Nreal) {
#pragma unroll
        for (int tm = 0; tm < 4; tm++) {
          const int token = mblock + wm + tm * 16 + l15;
          const f32x4 v = acc[tn][tm];
          const unsigned short* ip = Act + (size_t)token * K + n;
          const float i0 = h2f(ip[0]), i1 = h2f(ip[1]);
          const float i2 = h2f(ip[2]), i3 = h2f(ip[3]);
          const float d0 = tanhf(v[0]), d1 = tanhf(v[1]);
          const float d2 = tanhf(v[2]), d3 = tanhf(v[3]);
          ushort4 up, um;
          up.x = f2h(i0 + d0); up.y = f2h(i1 + d1);
          up.z = f2h(i2 + d2); up.w = f2h(i3 + d3);
          um.x = f2h(i0 - d0); um.y = f2h(i1 - d1);
          um.z = f2h(i2 - d2); um.w = f2h(i3 - d3);
          *(ushort4*)&OutB[(size_t)token * ldout + n] = up;
          *(ushort4*)&OutB[(size_t)token * ldout + Nreal + n] = um;
        }
      }
    }
  } else if constexpr (EPI == 1 || EPI == 2) {
    float loss = 0.f;
#pragma unroll
    for (int tn = 0; tn < 4; tn++) {
      const int n = nblock + wn + tn * 16 + quad * 4;
#pragma unroll
      for (int tm = 0; tm < 4; tm++) {
        const int token = mblock + wm + tm * 16 + l15;
        const f32x4 v = acc[tn][tm];
        const float nrm =
            sqrtf(v[0] * v[0] + v[1] * v[1] + v[2] * v[2] + v[3] * v[3]);
        const float inv = 1.f / (nrm + 1e-8f);
        ushort4 u;
        u.x = f2h(v[0] * inv); u.y = f2h(v[1] * inv);
        u.z = f2h(v[2] * inv); u.w = f2h(v[3] * inv);
        *(ushort4*)&OutB[(size_t)token * ldout + n] = u;
        if constexpr (EPI == 2) loss += fabsf(v[0] * inv);
      }
    }
    if constexpr (EPI == 2) {
#pragma unroll
      for (int off = 32; off > 0; off >>= 1) loss += __shfl_down(loss, off);
      if (lane == 0) lsum[wave] = loss;
      __syncthreads();
      if (tid == 0)
        atomicAdd(OutF,
                  (lsum[0] + lsum[1] + lsum[2] + lsum[3]) * (1.f / 8388608.f));
    }
  } else {  // EPI == 3 : head
#pragma unroll
    for (int tn = 0; tn < 4; tn++) {
      const int n = nblock + wn + tn * 16 + quad * 4;
      if (n < 257) {
#pragma unroll
        for (int tm = 0; tm < 4; tm++) {
          const int token = mblock + wm + tm * 16 + l15;
          const f32x4 v = acc[tn][tm];
#pragma unroll
          for (int r = 0; r < 4; r++)
            if (n + r < 257) OutF[(size_t)token * 257 + n + r] = v[r];
        }
      }
    }
  }
}

// ---------------------------------------------------------------------------
extern "C" void kernel_launch(void* const* d_in, const int* in_sizes, int n_in,
                              void* d_out, int out_size, void* d_ws,
                              size_t ws_size, hipStream_t stream) {
  const int*   x    = (const int*)d_in[0];
  const float* emb  = (const float*)d_in[1];
  const float* we0  = (const float*)d_in[2];
  const float* we1  = (const float*)d_in[3];
  const float* we2  = (const float*)d_in[4];
  const float* we3  = (const float*)d_in[5];
  const float* we4  = (const float*)d_in[6];
  const float* we5  = (const float*)d_in[7];
  const float* we6  = (const float*)d_in[8];
  const float* we7  = (const float*)d_in[9];
  const float* wlay = (const float*)d_in[10];
  const float* wh   = (const float*)d_in[11];
  float* out = (float*)d_out;

  // workspace layout (~142 MiB)
  char* p = (char*)d_ws;
  auto alloc = [&](size_t bytes) {
    void* r = (void*)p;
    p += (bytes + 255) & ~(size_t)255;
    return r;
  };
  unsigned short* act0 = (unsigned short*)alloc(32768ull * 1024 * 2);
  unsigned short* act1 = (unsigned short*)alloc(32768ull * 1024 * 2);
  unsigned short* E4 = (unsigned short*)alloc(128 * 64 * 2);
  unsigned short* E5 = (unsigned short*)alloc(128 * 128 * 2);
  unsigned short* E6 = (unsigned short*)alloc(256 * 256 * 2);
  unsigned short* E7 = (unsigned short*)alloc(512 * 512 * 2);
  unsigned short* EL = (unsigned short*)alloc(6ull * 1024 * 1024 * 2);
  unsigned short* WH = (unsigned short*)alloc(384 * 1024 * 2);

  // zero the stability-loss slot (d_out is poisoned before every launch)
  hipMemsetAsync(out + 8421376, 0, 4, stream);

  // fused weight prep (all Hamilton expansions + head conversion)
  prep_weights<<<dim3(27488), 256, 0, stream>>>(we4, we5, we6, we7, wlay, wh,
                                                E4, E5, E6, E7, EL, WH);

  // embed + expansion steps 0..3 -> act0 [32768][64] fp16
  embed_expand<<<dim3(128), 256, 0, stream>>>(x, emb, we0, we1, we2, we3, act0);

  // expansion steps 4..7 as fused GEMMs (grid x = n-tiles, y = token-tiles)
  gemm_epi<0, 64><<<dim3(1, 256), 256, 0, stream>>>(E4, act0, act1, nullptr,
                                                    64, 128);
  gemm_epi<0, 128><<<dim3(1, 256), 256, 0, stream>>>(E5, act1, act0, nullptr,
                                                     128, 256);
  gemm_epi<0, 256><<<dim3(2, 256), 256, 0, stream>>>(E6, act0, act1, nullptr,
                                                     256, 512);
  gemm_epi<0, 512><<<dim3(4, 256), 256, 0, stream>>>(E7, act1, act0, nullptr,
                                                     512, 1024);

  // 6 quaternion-linear + normalize layers (last also accumulates loss)
  unsigned short* a = act0;
  unsigned short* b = act1;
  for (int d = 0; d < 5; d++) {
    gemm_epi<1, 1024><<<dim3(8, 256), 256, 0, stream>>>(
        EL + (size_t)d * 1048576, a, b, nullptr, 1024, 1024);
    unsigned short* t = a; a = b; b = t;
  }
  gemm_epi<2, 1024><<<dim3(8, 256), 256, 0, stream>>>(
      EL + 5ull * 1048576, a, b, out + 8421376, 1024, 1024);
  { unsigned short* t = a; a = b; b = t; }

  // head: logits = h @ w_head^T  (N padded 257 -> 384, masked stores)
  gemm_epi<3, 1024><<<dim3(3, 256), 256, 0, stream>>>(WH, a, nullptr, out, 257,
                                                      0);
}

// Round 8
// 1077.486 us; speedup vs baseline: 1.3474x; 1.3474x over previous
//
#include <hip/hip_runtime.h>

// ---------------------------------------------------------------------------
// H2Q knot kernel: embed -> 8 doubling quaternion expansion steps ->
// 6 quaternion-linear+normalize layers -> vocab head (+ stability loss).
// R8 = R5's exact memory structure (W+Act staged via global_load_lds,
// single-buffered BK=64, stage/barrier/compute/barrier, XCD swizzle)
// + K as a template parameter with the K-loop fully unrolled.
// Rationale: R7 showed full unroll cuts VALUBusy 48%->9% (loop addressing
// was R5's dominant VALU load), but R7's W-direct-to-VGPR prefetch blew up
// VGPR (80->132) and put 8 extra loads inside every vmcnt(0)+barrier drain,
// collapsing occupancy (27->11%). R8 harvests the unroll alone.
// ---------------------------------------------------------------------------

typedef _Float16 f16x8 __attribute__((ext_vector_type(8)));
typedef float    f32x4 __attribute__((ext_vector_type(4)));

#define GL2LDS16(gp, lp) __builtin_amdgcn_global_load_lds(                     \
    (const __attribute__((address_space(1))) void*)(gp),                       \
    (__attribute__((address_space(3))) void*)(lp), 16, 0, 0)

__device__ __forceinline__ unsigned short f2h(float f) {
  union { _Float16 h; unsigned short u; } c;
  c.h = (_Float16)f;                       // RNE
  return c.u;
}
__device__ __forceinline__ float h2f(unsigned short u) {
  union { unsigned short u; _Float16 h; } c;
  c.u = u;
  return (float)c.h;
}

// ---------------------------------------------------------------------------
// Fused weight prep: all Hamilton expansions + head conversion in ONE kernel.
// Hamilton block (E[n][k], n=4o+a, k=4i+b):
//  a=0: [ Wr,-Wi,-Wj,-Wk]  a=1: [ Wi, Wr, Wk,-Wj]
//  a=2: [ Wj,-Wk, Wr, Wi]  a=3: [ Wk, Wj,-Wi, Wr]
// ---------------------------------------------------------------------------
__device__ __forceinline__ void expand_one(const float* __restrict__ w,
                                           unsigned short* __restrict__ out,
                                           int cq, int kbits, int id) {
  const int K = 1 << kbits;
  const int n = id >> kbits;
  const int k = id & (K - 1);
  float val = 0.f;
  if (n < 4 * cq) {
    const int o = n >> 2, a = n & 3, i = k >> 2, b = k & 3;
    const int   comp[4][4] = {{0,1,2,3},{1,0,3,2},{2,3,0,1},{3,2,1,0}};
    const float sgn [4][4] = {{1.f,-1.f,-1.f,-1.f},{1.f,1.f,1.f,-1.f},
                              {1.f,-1.f,1.f,1.f},{1.f,1.f,-1.f,1.f}};
    val = sgn[a][b] * w[comp[a][b] * cq * cq + o * cq + i];
  }
  out[id] = f2h(val);
}

__global__ __launch_bounds__(256) void prep_weights(
    const float* __restrict__ we4, const float* __restrict__ we5,
    const float* __restrict__ we6, const float* __restrict__ we7,
    const float* __restrict__ wlay, const float* __restrict__ wh,
    unsigned short* __restrict__ E4, unsigned short* __restrict__ E5,
    unsigned short* __restrict__ E6, unsigned short* __restrict__ E7,
    unsigned short* __restrict__ EL, unsigned short* __restrict__ WH) {
  const int b = blockIdx.x;
  const int tid = threadIdx.x;
  if (b < 32) {
    expand_one(we4, E4, 16, 6, b * 256 + tid);
  } else if (b < 96) {
    expand_one(we5, E5, 32, 7, (b - 32) * 256 + tid);
  } else if (b < 352) {
    expand_one(we6, E6, 64, 8, (b - 96) * 256 + tid);
  } else if (b < 1376) {
    expand_one(we7, E7, 128, 9, (b - 352) * 256 + tid);
  } else if (b < 25952) {
    const int d = (b - 1376) >> 12;               // 4096 blocks per layer
    const int id = ((b - 1376) & 4095) * 256 + tid;
    expand_one(wlay + (size_t)d * 262144, EL + (size_t)d * 1048576, 256, 10,
               id);
  } else {
    const int id = (b - 25952) * 256 + tid;       // 393216 head elements
    const int v = id >> 10, k = id & 1023;
    WH[id] = f2h(v < 257 ? wh[v * 1024 + k] : 0.f);
  }
}

// ---------------------------------------------------------------------------
// Embed + expansion steps 0..3 (cq=1,2,4,8), one token per thread (weights are
// wave-uniform -> scalar-cached broadcast loads). Output: fp16 [32768][64].
// ---------------------------------------------------------------------------
template <int CQ>
__device__ __forceinline__ void exp_step(float (&q)[16][4],
                                         const float* __restrict__ w) {
  float d[CQ][4];
#pragma unroll
  for (int o = 0; o < CQ; o++) {
    float pr = 0.f, pi = 0.f, pj = 0.f, pk = 0.f;
#pragma unroll
    for (int i = 0; i < CQ; i++) {
      const float wr = w[0 * CQ * CQ + o * CQ + i];
      const float wi = w[1 * CQ * CQ + o * CQ + i];
      const float wj = w[2 * CQ * CQ + o * CQ + i];
      const float wk = w[3 * CQ * CQ + o * CQ + i];
      const float qr = q[i][0], qi = q[i][1], qj = q[i][2], qk = q[i][3];
      pr += wr * qr - wi * qi - wj * qj - wk * qk;
      pi += wi * qr + wr * qi + wk * qj - wj * qk;
      pj += wj * qr - wk * qi + wr * qj + wi * qk;
      pk += wk * qr + wj * qi - wi * qj + wr * qk;
    }
    d[o][0] = tanhf(pr); d[o][1] = tanhf(pi);
    d[o][2] = tanhf(pj); d[o][3] = tanhf(pk);
  }
#pragma unroll
  for (int o = 0; o < CQ; o++)
#pragma unroll
    for (int a = 0; a < 4; a++) {
      const float dd = d[o][a], qq = q[o][a];
      q[o][a]      = qq + dd;
      q[CQ + o][a] = qq - dd;
    }
}

__global__ __launch_bounds__(256) void embed_expand(
    const int* __restrict__ x, const float* __restrict__ emb,
    const float* __restrict__ w0, const float* __restrict__ w1,
    const float* __restrict__ w2, const float* __restrict__ w3,
    unsigned short* __restrict__ out) {
  const int t = blockIdx.x * 256 + threadIdx.x;  // 32768 tokens
  float q[16][4];
  const int v = x[t];
  const float4 e = *(const float4*)(emb + v * 4);
  q[0][0] = e.x; q[0][1] = e.y; q[0][2] = e.z; q[0][3] = e.w;
  exp_step<1>(q, w0);
  exp_step<2>(q, w1);
  exp_step<4>(q, w2);
  exp_step<8>(q, w3);
  ushort4* o4 = (ushort4*)(out + (size_t)t * 64);
#pragma unroll
  for (int c = 0; c < 16; c++) {
    ushort4 u;
    u.x = f2h(q[c][0]); u.y = f2h(q[c][1]);
    u.z = f2h(q[c][2]); u.w = f2h(q[c][3]);
    o4[c] = u;
  }
}

// ---------------------------------------------------------------------------
// Fused GEMM: D[n][token] = sum_k W[n][k] * Act[token][k] (fp16, k-contig).
// Grid (Gx = #n-tiles, 256 token-tiles) with XCD swizzle: L=by*Gx+bx,
// xcd=L%8 owns token-tiles [32*xcd,32*xcd+32), n fastest -> per-XCD working
// set ~4MB = one L2.
// 128x128 block tile, 4 waves each 64x64 (4x4 of 16x16x32 MFMA, A=W, B=Act).
// C/D: col=token=lane&15, row=n=(lane>>4)*4+reg -> lane owns a quaternion.
// K-loop: BK=64 (two 32-k sub-tiles in 4 separate 8KB LDS regions), one
// barrier pair per 64 k; K is a template param -> FULL UNROLL: glds sources
// are base+immediate, ds_read addresses loop-invariant, per-iter VALU ~0.
// EPI: 0 = expansion (delta=tanh, write q+delta | q-delta, width 2*Nreal)
//      1 = quaternion normalize -> fp16 [token][1024]
//      2 = EPI1 + stability-loss accumulation (mean |r|)
//      3 = head: fp32 store to d_out[token*257 + n], n < 257
// ---------------------------------------------------------------------------
template <int EPI, int K>
__global__ __launch_bounds__(256) void gemm_epi(
    const unsigned short* __restrict__ W,
    const unsigned short* __restrict__ Act,
    unsigned short* __restrict__ OutB, float* __restrict__ OutF,
    int Nreal, int ldout) {
  __shared__ unsigned short WtL[128 * 32];
  __shared__ unsigned short WtH[128 * 32];
  __shared__ unsigned short AtL[128 * 32];
  __shared__ unsigned short AtH[128 * 32];
  __shared__ float lsum[4];

  const int tid  = threadIdx.x;
  const int wave = tid >> 6;
  const int lane = tid & 63;
  const int l15  = lane & 15;
  const int quad = lane >> 4;

  const int Gx = gridDim.x;
  const int L  = blockIdx.y * Gx + blockIdx.x;
  const int j  = L & 7;
  const int s  = L >> 3;
  const int nblock = (s % Gx) * 128;               // n (output feature)
  const int mblock = (32 * j + s / Gx) * 128;      // token
  const int wn = (wave & 1) * 64;
  const int wm = (wave >> 1) * 64;

  f32x4 acc[4][4];
  const f32x4 zero = {0.f, 0.f, 0.f, 0.f};
#pragma unroll
  for (int a = 0; a < 4; a++)
#pragma unroll
    for (int b = 0; b < 4; b++) acc[a][b] = zero;

  // staging: lane chunk row = tid>>2 (global row), sub = tid&3 (16B of 64B)
  const int row0 = tid >> 2;
  const int sub  = tid & 3;
  const unsigned short* gW0 = W   + (size_t)(nblock + row0)      * K + sub * 8;
  const unsigned short* gW1 = W   + (size_t)(nblock + row0 + 64) * K + sub * 8;
  const unsigned short* gA0 = Act + (size_t)(mblock + row0)      * K + sub * 8;
  const unsigned short* gA1 = Act + (size_t)(mblock + row0 + 64) * K + sub * 8;
  unsigned short* lWL0 = &WtL[wave * 512];
  unsigned short* lWL1 = &WtL[2048 + wave * 512];
  unsigned short* lWH0 = &WtH[wave * 512];
  unsigned short* lWH1 = &WtH[2048 + wave * 512];
  unsigned short* lAL0 = &AtL[wave * 512];
  unsigned short* lAL1 = &AtL[2048 + wave * 512];
  unsigned short* lAH0 = &AtH[wave * 512];
  unsigned short* lAH1 = &AtH[2048 + wave * 512];

  constexpr int NIT = K / 64;
#pragma unroll
  for (int it = 0; it < NIT; it++) {
    const int kb = it * 64;   // compile-time under full unroll -> imm offsets
    GL2LDS16(gW0 + kb,      lWL0);
    GL2LDS16(gW1 + kb,      lWL1);
    GL2LDS16(gW0 + kb + 32, lWH0);
    GL2LDS16(gW1 + kb + 32, lWH1);
    GL2LDS16(gA0 + kb,      lAL0);
    GL2LDS16(gA1 + kb,      lAL1);
    GL2LDS16(gA0 + kb + 32, lAH0);
    GL2LDS16(gA1 + kb + 32, lAH1);
    __syncthreads();

    {
      f16x8 afr[4], bfr[4];
#pragma unroll
      for (int tn = 0; tn < 4; tn++)
        afr[tn] = *(const f16x8*)&WtL[(wn + tn * 16 + l15) * 32 + quad * 8];
#pragma unroll
      for (int tm = 0; tm < 4; tm++)
        bfr[tm] = *(const f16x8*)&AtL[(wm + tm * 16 + l15) * 32 + quad * 8];
#pragma unroll
      for (int tn = 0; tn < 4; tn++)
#pragma unroll
        for (int tm = 0; tm < 4; tm++)
          acc[tn][tm] = __builtin_amdgcn_mfma_f32_16x16x32_f16(
              afr[tn], bfr[tm], acc[tn][tm], 0, 0, 0);
    }
    {
      f16x8 afr[4], bfr[4];
#pragma unroll
      for (int tn = 0; tn < 4; tn++)
        afr[tn] = *(const f16x8*)&WtH[(wn + tn * 16 + l15) * 32 + quad * 8];
#pragma unroll
      for (int tm = 0; tm < 4; tm++)
        bfr[tm] = *(const f16x8*)&AtH[(wm + tm * 16 + l15) * 32 + quad * 8];
#pragma unroll
      for (int tn = 0; tn < 4; tn++)
#pragma unroll
        for (int tm = 0; tm < 4; tm++)
          acc[tn][tm] = __builtin_amdgcn_mfma_f32_16x16x32_f16(
              afr[tn], bfr[tm], acc[tn][tm], 0, 0, 0);
    }
    __syncthreads();
  }

  if constexpr (EPI == 0) {
#pragma unroll
    for (int tn = 0; tn < 4; tn++) {
      const int n = nblock + wn + tn * 16 + quad * 4;
      if (n < Nreal) {
#pragma unroll
        for (int tm = 0; tm < 4; tm++) {
          const int token = mblock + wm + tm * 16 + l15;
          const f32x4 v = acc[tn][tm];
          const unsigned short* ip = Act + (size_t)token * K + n;
          const float i0 = h2f(ip[0]), i1 = h2f(ip[1]);
          const float i2 = h2f(ip[2]), i3 = h2f(ip[3]);
          const float d0 = tanhf(v[0]), d1 = tanhf(v[1]);
          const float d2 = tanhf(v[2]), d3 = tanhf(v[3]);
          ushort4 up, um;
          up.x = f2h(i0 + d0); up.y = f2h(i1 + d1);
          up.z = f2h(i2 + d2); up.w = f2h(i3 + d3);
          um.x = f2h(i0 - d0); um.y = f2h(i1 - d1);
          um.z = f2h(i2 - d2); um.w = f2h(i3 - d3);
          *(ushort4*)&OutB[(size_t)token * ldout + n] = up;
          *(ushort4*)&OutB[(size_t)token * ldout + Nreal + n] = um;
        }
      }
    }
  } else if constexpr (EPI == 1 || EPI == 2) {
    float loss = 0.f;
#pragma unroll
    for (int tn = 0; tn < 4; tn++) {
      const int n = nblock + wn + tn * 16 + quad * 4;
#pragma unroll
      for (int tm = 0; tm < 4; tm++) {
        const int token = mblock + wm + tm * 16 + l15;
        const f32x4 v = acc[tn][tm];
        const float nrm =
            sqrtf(v[0] * v[0] + v[1] * v[1] + v[2] * v[2] + v[3] * v[3]);
        const float inv = 1.f / (nrm + 1e-8f);
        ushort4 u;
        u.x = f2h(v[0] * inv); u.y = f2h(v[1] * inv);
        u.z = f2h(v[2] * inv); u.w = f2h(v[3] * inv);
        *(ushort4*)&OutB[(size_t)token * ldout + n] = u;
        if constexpr (EPI == 2) loss += fabsf(v[0] * inv);
      }
    }
    if constexpr (EPI == 2) {
#pragma unroll
      for (int off = 32; off > 0; off >>= 1) loss += __shfl_down(loss, off);
      if (lane == 0) lsum[wave] = loss;
      __syncthreads();
      if (tid == 0)
        atomicAdd(OutF,
                  (lsum[0] + lsum[1] + lsum[2] + lsum[3]) * (1.f / 8388608.f));
    }
  } else {  // EPI == 3 : head
#pragma unroll
    for (int tn = 0; tn < 4; tn++) {
      const int n = nblock + wn + tn * 16 + quad * 4;
      if (n < 257) {
#pragma unroll
        for (int tm = 0; tm < 4; tm++) {
          const int token = mblock + wm + tm * 16 + l15;
          const f32x4 v = acc[tn][tm];
#pragma unroll
          for (int r = 0; r < 4; r++)
            if (n + r < 257) OutF[(size_t)token * 257 + n + r] = v[r];
        }
      }
    }
  }
}

// ---------------------------------------------------------------------------
extern "C" void kernel_launch(void* const* d_in, const int* in_sizes, int n_in,
                              void* d_out, int out_size, void* d_ws,
                              size_t ws_size, hipStream_t stream) {
  const int*   x    = (const int*)d_in[0];
  const float* emb  = (const float*)d_in[1];
  const float* we0  = (const float*)d_in[2];
  const float* we1  = (const float*)d_in[3];
  const float* we2  = (const float*)d_in[4];
  const float* we3  = (const float*)d_in[5];
  const float* we4  = (const float*)d_in[6];
  const float* we5  = (const float*)d_in[7];
  const float* we6  = (const float*)d_in[8];
  const float* we7  = (const float*)d_in[9];
  const float* wlay = (const float*)d_in[10];
  const float* wh   = (const float*)d_in[11];
  float* out = (float*)d_out;

  // workspace layout (~142 MiB)
  char* p = (char*)d_ws;
  auto alloc = [&](size_t bytes) {
    void* r = (void*)p;
    p += (bytes + 255) & ~(size_t)255;
    return r;
  };
  unsigned short* act0 = (unsigned short*)alloc(32768ull * 1024 * 2);
  unsigned short* act1 = (unsigned short*)alloc(32768ull * 1024 * 2);
  unsigned short* E4 = (unsigned short*)alloc(128 * 64 * 2);
  unsigned short* E5 = (unsigned short*)alloc(128 * 128 * 2);
  unsigned short* E6 = (unsigned short*)alloc(256 * 256 * 2);
  unsigned short* E7 = (unsigned short*)alloc(512 * 512 * 2);
  unsigned short* EL = (unsigned short*)alloc(6ull * 1024 * 1024 * 2);
  unsigned short* WH = (unsigned short*)alloc(384 * 1024 * 2);

  // zero the stability-loss slot (d_out is poisoned before every launch)
  hipMemsetAsync(out + 8421376, 0, 4, stream);

  // fused weight prep (all Hamilton expansions + head conversion)
  prep_weights<<<dim3(27488), 256, 0, stream>>>(we4, we5, we6, we7, wlay, wh,
                                                E4, E5, E6, E7, EL, WH);

  // embed + expansion steps 0..3 -> act0 [32768][64] fp16
  embed_expand<<<dim3(128), 256, 0, stream>>>(x, emb, we0, we1, we2, we3, act0);

  // expansion steps 4..7 as fused GEMMs (grid x = n-tiles, y = token-tiles)
  gemm_epi<0, 64><<<dim3(1, 256), 256, 0, stream>>>(E4, act0, act1, nullptr,
                                                    64, 128);
  gemm_epi<0, 128><<<dim3(1, 256), 256, 0, stream>>>(E5, act1, act0, nullptr,
                                                     128, 256);
  gemm_epi<0, 256><<<dim3(2, 256), 256, 0, stream>>>(E6, act0, act1, nullptr,
                                                     256, 512);
  gemm_epi<0, 512><<<dim3(4, 256), 256, 0, stream>>>(E7, act1, act0, nullptr,
                                                     512, 1024);

  // 6 quaternion-linear + normalize layers (last also accumulates loss)
  unsigned short* a = act0;
  unsigned short* b = act1;
  for (int d = 0; d < 5; d++) {
    gemm_epi<1, 1024><<<dim3(8, 256), 256, 0, stream>>>(
        EL + (size_t)d * 1048576, a, b, nullptr, 1024, 1024);
    unsigned short* t = a; a = b; b = t;
  }
  gemm_epi<2, 1024><<<dim3(8, 256), 256, 0, stream>>>(
      EL + 5ull * 1048576, a, b, out + 8421376, 1024, 1024);
  { unsigned short* t = a; a = b; b = t; }

  // head: logits = h @ w_head^T  (N padded 257 -> 384, masked stores)
  gemm_epi<3, 1024><<<dim3(3, 256), 256, 0, stream>>>(WH, a, nullptr, out, 257,
                                                      0);
}

// Round 9
// 882.086 us; speedup vs baseline: 1.6459x; 1.2215x over previous
//
#include <hip/hip_runtime.h>

// ---------------------------------------------------------------------------
// H2Q knot kernel: embed -> 8 doubling quaternion expansion steps ->
// 6 quaternion-linear+normalize layers -> vocab head (+ stability loss).
// R9 = R5's memory structure + TRUE LDS double-buffering with ONE barrier
// per BK=64 iteration (dynamic K-loop).
// Diagnosis from R5/R7/R8: the single-buffer stage->barrier->compute
// structure exposes full L2/HBM latency at every barrier (R5: MfmaUtil 30%);
// removing VALU filler (R8 unroll) makes it WORSE (24%, lockstep bursts);
// register-held W prefetch (R7) kills occupancy (VGPR 132). R9 pipelines at
// LDS level: stage iter i+1 right after barrier i, consume one full MFMA
// block later -> drain covered by compute. 16 barriers/K=1024 vs 32.
// LDS 64.5KB -> 2 blocks/CU (8 waves), VGPR ~80 unchanged.
// ---------------------------------------------------------------------------

typedef _Float16 f16x8 __attribute__((ext_vector_type(8)));
typedef float    f32x4 __attribute__((ext_vector_type(4)));

#define GL2LDS16(gp, lp) __builtin_amdgcn_global_load_lds(                     \
    (const __attribute__((address_space(1))) void*)(gp),                       \
    (__attribute__((address_space(3))) void*)(lp), 16, 0, 0)

__device__ __forceinline__ unsigned short f2h(float f) {
  union { _Float16 h; unsigned short u; } c;
  c.h = (_Float16)f;                       // RNE
  return c.u;
}
__device__ __forceinline__ float h2f(unsigned short u) {
  union { unsigned short u; _Float16 h; } c;
  c.u = u;
  return (float)c.h;
}

// ---------------------------------------------------------------------------
// Fused weight prep: all Hamilton expansions + head conversion in ONE kernel.
// Hamilton block (E[n][k], n=4o+a, k=4i+b):
//  a=0: [ Wr,-Wi,-Wj,-Wk]  a=1: [ Wi, Wr, Wk,-Wj]
//  a=2: [ Wj,-Wk, Wr, Wi]  a=3: [ Wk, Wj,-Wi, Wr]
// ---------------------------------------------------------------------------
__device__ __forceinline__ void expand_one(const float* __restrict__ w,
                                           unsigned short* __restrict__ out,
                                           int cq, int kbits, int id) {
  const int K = 1 << kbits;
  const int n = id >> kbits;
  const int k = id & (K - 1);
  float val = 0.f;
  if (n < 4 * cq) {
    const int o = n >> 2, a = n & 3, i = k >> 2, b = k & 3;
    const int   comp[4][4] = {{0,1,2,3},{1,0,3,2},{2,3,0,1},{3,2,1,0}};
    const float sgn [4][4] = {{1.f,-1.f,-1.f,-1.f},{1.f,1.f,1.f,-1.f},
                              {1.f,-1.f,1.f,1.f},{1.f,1.f,-1.f,1.f}};
    val = sgn[a][b] * w[comp[a][b] * cq * cq + o * cq + i];
  }
  out[id] = f2h(val);
}

__global__ __launch_bounds__(256) void prep_weights(
    const float* __restrict__ we4, const float* __restrict__ we5,
    const float* __restrict__ we6, const float* __restrict__ we7,
    const float* __restrict__ wlay, const float* __restrict__ wh,
    unsigned short* __restrict__ E4, unsigned short* __restrict__ E5,
    unsigned short* __restrict__ E6, unsigned short* __restrict__ E7,
    unsigned short* __restrict__ EL, unsigned short* __restrict__ WH) {
  const int b = blockIdx.x;
  const int tid = threadIdx.x;
  if (b < 32) {
    expand_one(we4, E4, 16, 6, b * 256 + tid);
  } else if (b < 96) {
    expand_one(we5, E5, 32, 7, (b - 32) * 256 + tid);
  } else if (b < 352) {
    expand_one(we6, E6, 64, 8, (b - 96) * 256 + tid);
  } else if (b < 1376) {
    expand_one(we7, E7, 128, 9, (b - 352) * 256 + tid);
  } else if (b < 25952) {
    const int d = (b - 1376) >> 12;               // 4096 blocks per layer
    const int id = ((b - 1376) & 4095) * 256 + tid;
    expand_one(wlay + (size_t)d * 262144, EL + (size_t)d * 1048576, 256, 10,
               id);
  } else {
    const int id = (b - 25952) * 256 + tid;       // 393216 head elements
    const int v = id >> 10, k = id & 1023;
    WH[id] = f2h(v < 257 ? wh[v * 1024 + k] : 0.f);
  }
}

// ---------------------------------------------------------------------------
// Embed + expansion steps 0..3 (cq=1,2,4,8), one token per thread (weights are
// wave-uniform -> scalar-cached broadcast loads). Output: fp16 [32768][64].
// ---------------------------------------------------------------------------
template <int CQ>
__device__ __forceinline__ void exp_step(float (&q)[16][4],
                                         const float* __restrict__ w) {
  float d[CQ][4];
#pragma unroll
  for (int o = 0; o < CQ; o++) {
    float pr = 0.f, pi = 0.f, pj = 0.f, pk = 0.f;
#pragma unroll
    for (int i = 0; i < CQ; i++) {
      const float wr = w[0 * CQ * CQ + o * CQ + i];
      const float wi = w[1 * CQ * CQ + o * CQ + i];
      const float wj = w[2 * CQ * CQ + o * CQ + i];
      const float wk = w[3 * CQ * CQ + o * CQ + i];
      const float qr = q[i][0], qi = q[i][1], qj = q[i][2], qk = q[i][3];
      pr += wr * qr - wi * qi - wj * qj - wk * qk;
      pi += wi * qr + wr * qi + wk * qj - wj * qk;
      pj += wj * qr - wk * qi + wr * qj + wi * qk;
      pk += wk * qr + wj * qi - wi * qj + wr * qk;
    }
    d[o][0] = tanhf(pr); d[o][1] = tanhf(pi);
    d[o][2] = tanhf(pj); d[o][3] = tanhf(pk);
  }
#pragma unroll
  for (int o = 0; o < CQ; o++)
#pragma unroll
    for (int a = 0; a < 4; a++) {
      const float dd = d[o][a], qq = q[o][a];
      q[o][a]      = qq + dd;
      q[CQ + o][a] = qq - dd;
    }
}

__global__ __launch_bounds__(256) void embed_expand(
    const int* __restrict__ x, const float* __restrict__ emb,
    const float* __restrict__ w0, const float* __restrict__ w1,
    const float* __restrict__ w2, const float* __restrict__ w3,
    unsigned short* __restrict__ out) {
  const int t = blockIdx.x * 256 + threadIdx.x;  // 32768 tokens
  float q[16][4];
  const int v = x[t];
  const float4 e = *(const float4*)(emb + v * 4);
  q[0][0] = e.x; q[0][1] = e.y; q[0][2] = e.z; q[0][3] = e.w;
  exp_step<1>(q, w0);
  exp_step<2>(q, w1);
  exp_step<4>(q, w2);
  exp_step<8>(q, w3);
  ushort4* o4 = (ushort4*)(out + (size_t)t * 64);
#pragma unroll
  for (int c = 0; c < 16; c++) {
    ushort4 u;
    u.x = f2h(q[c][0]); u.y = f2h(q[c][1]);
    u.z = f2h(q[c][2]); u.w = f2h(q[c][3]);
    o4[c] = u;
  }
}

// ---------------------------------------------------------------------------
// Fused GEMM: D[n][token] = sum_k W[n][k] * Act[token][k] (fp16, k-contig).
// Grid (Gx = #n-tiles, 256 token-tiles) with XCD swizzle: L=by*Gx+bx,
// xcd=L%8 owns token-tiles [32*xcd,32*xcd+32), n fastest -> per-XCD working
// set ~4MB = one L2.
// 128x128 block tile, 4 waves each 64x64 (4x4 of 16x16x32 MFMA, A=W, B=Act).
// C/D: col=token=lane&15, row=n=(lane>>4)*4+reg -> lane owns a quaternion.
// K-loop: BK=64, DOUBLE-BUFFERED LDS (2 x {WtL,WtH,AtL,AtH} 8KB regions),
// ONE barrier per iteration:
//   barrier(i) -> stage iter i+1 into buf nxt -> ds_read buf cur -> 32 MFMA
// The glds drained at barrier(i+1) were issued one full compute block
// (~310 cyc) earlier -> latency covered. Overwrite of buf nxt is safe: its
// iter i-1 ds_reads completed before any wave passed barrier(i).
// EPI: 0 = expansion (delta=tanh, write q+delta | q-delta, width 2*Nreal)
//      1 = quaternion normalize -> fp16 [token][1024]
//      2 = EPI1 + stability-loss accumulation (mean |r|)
//      3 = head: fp32 store to d_out[token*257 + n], n < 257
// ---------------------------------------------------------------------------
template <int EPI>
__global__ __launch_bounds__(256) void gemm_epi(
    const unsigned short* __restrict__ W,
    const unsigned short* __restrict__ Act,
    unsigned short* __restrict__ OutB, float* __restrict__ OutF,
    int K, int Nreal, int ldout) {
  __shared__ unsigned short WtL[2][4096];
  __shared__ unsigned short WtH[2][4096];
  __shared__ unsigned short AtL[2][4096];
  __shared__ unsigned short AtH[2][4096];
  __shared__ float lsum[4];

  const int tid  = threadIdx.x;
  const int wave = tid >> 6;
  const int lane = tid & 63;
  const int l15  = lane & 15;
  const int quad = lane >> 4;

  const int Gx = gridDim.x;
  const int L  = blockIdx.y * Gx + blockIdx.x;
  const int j  = L & 7;
  const int s  = L >> 3;
  const int nblock = (s % Gx) * 128;               // n (output feature)
  const int mblock = (32 * j + s / Gx) * 128;      // token
  const int wn = (wave & 1) * 64;
  const int wm = (wave >> 1) * 64;

  f32x4 acc[4][4];
  const f32x4 zero = {0.f, 0.f, 0.f, 0.f};
#pragma unroll
  for (int a = 0; a < 4; a++)
#pragma unroll
    for (int b = 0; b < 4; b++) acc[a][b] = zero;

  // staging: lane chunk row = tid>>2 (global row), sub = tid&3 (16B of 64B)
  const int row0 = tid >> 2;
  const int sub  = tid & 3;
  const unsigned short* gW0 = W   + (size_t)(nblock + row0)      * K + sub * 8;
  const unsigned short* gW1 = W   + (size_t)(nblock + row0 + 64) * K + sub * 8;
  const unsigned short* gA0 = Act + (size_t)(mblock + row0)      * K + sub * 8;
  const unsigned short* gA1 = Act + (size_t)(mblock + row0 + 64) * K + sub * 8;
  const int lofs0 = wave * 512;          // rows 0..63 region
  const int lofs1 = 2048 + wave * 512;   // rows 64..127 region

  const int NIT = K >> 6;

  // prologue: stage iter 0 into buffer 0
  GL2LDS16(gW0,      &WtL[0][lofs0]);
  GL2LDS16(gW1,      &WtL[0][lofs1]);
  GL2LDS16(gW0 + 32, &WtH[0][lofs0]);
  GL2LDS16(gW1 + 32, &WtH[0][lofs1]);
  GL2LDS16(gA0,      &AtL[0][lofs0]);
  GL2LDS16(gA1,      &AtL[0][lofs1]);
  GL2LDS16(gA0 + 32, &AtH[0][lofs0]);
  GL2LDS16(gA1 + 32, &AtH[0][lofs1]);

  for (int it = 0; it < NIT; it++) {
    const int cur = it & 1, nxt = cur ^ 1;
    __syncthreads();   // buf[cur] staged (glds issued one compute block ago)
    if (it + 1 < NIT) {
      const int kb = (it + 1) * 64;
      GL2LDS16(gW0 + kb,      &WtL[nxt][lofs0]);
      GL2LDS16(gW1 + kb,      &WtL[nxt][lofs1]);
      GL2LDS16(gW0 + kb + 32, &WtH[nxt][lofs0]);
      GL2LDS16(gW1 + kb + 32, &WtH[nxt][lofs1]);
      GL2LDS16(gA0 + kb,      &AtL[nxt][lofs0]);
      GL2LDS16(gA1 + kb,      &AtL[nxt][lofs1]);
      GL2LDS16(gA0 + kb + 32, &AtH[nxt][lofs0]);
      GL2LDS16(gA1 + kb + 32, &AtH[nxt][lofs1]);
    }
    {
      f16x8 afr[4], bfr[4];
#pragma unroll
      for (int tn = 0; tn < 4; tn++)
        afr[tn] =
            *(const f16x8*)&WtL[cur][(wn + tn * 16 + l15) * 32 + quad * 8];
#pragma unroll
      for (int tm = 0; tm < 4; tm++)
        bfr[tm] =
            *(const f16x8*)&AtL[cur][(wm + tm * 16 + l15) * 32 + quad * 8];
#pragma unroll
      for (int tn = 0; tn < 4; tn++)
#pragma unroll
        for (int tm = 0; tm < 4; tm++)
          acc[tn][tm] = __builtin_amdgcn_mfma_f32_16x16x32_f16(
              afr[tn], bfr[tm], acc[tn][tm], 0, 0, 0);
    }
    {
      f16x8 afr[4], bfr[4];
#pragma unroll
      for (int tn = 0; tn < 4; tn++)
        afr[tn] =
            *(const f16x8*)&WtH[cur][(wn + tn * 16 + l15) * 32 + quad * 8];
#pragma unroll
      for (int tm = 0; tm < 4; tm++)
        bfr[tm] =
            *(const f16x8*)&AtH[cur][(wm + tm * 16 + l15) * 32 + quad * 8];
#pragma unroll
      for (int tn = 0; tn < 4; tn++)
#pragma unroll
        for (int tm = 0; tm < 4; tm++)
          acc[tn][tm] = __builtin_amdgcn_mfma_f32_16x16x32_f16(
              afr[tn], bfr[tm], acc[tn][tm], 0, 0, 0);
    }
  }

  if constexpr (EPI == 0) {
#pragma unroll
    for (int tn = 0; tn < 4; tn++) {
      const int n = nblock + wn + tn * 16 + quad * 4;
      if (n < Nreal) {
#pragma unroll
        for (int tm = 0; tm < 4; tm++) {
          const int token = mblock + wm + tm * 16 + l15;
          const f32x4 v = acc[tn][tm];
          const unsigned short* ip = Act + (size_t)token * K + n;
          const float i0 = h2f(ip[0]), i1 = h2f(ip[1]);
          const float i2 = h2f(ip[2]), i3 = h2f(ip[3]);
          const float d0 = tanhf(v[0]), d1 = tanhf(v[1]);
          const float d2 = tanhf(v[2]), d3 = tanhf(v[3]);
          ushort4 up, um;
          up.x = f2h(i0 + d0); up.y = f2h(i1 + d1);
          up.z = f2h(i2 + d2); up.w = f2h(i3 + d3);
          um.x = f2h(i0 - d0); um.y = f2h(i1 - d1);
          um.z = f2h(i2 - d2); um.w = f2h(i3 - d3);
          *(ushort4*)&OutB[(size_t)token * ldout + n] = up;
          *(ushort4*)&OutB[(size_t)token * ldout + Nreal + n] = um;
        }
      }
    }
  } else if constexpr (EPI == 1 || EPI == 2) {
    float loss = 0.f;
#pragma unroll
    for (int tn = 0; tn < 4; tn++) {
      const int n = nblock + wn + tn * 16 + quad * 4;
#pragma unroll
      for (int tm = 0; tm < 4; tm++) {
        const int token = mblock + wm + tm * 16 + l15;
        const f32x4 v = acc[tn][tm];
        const float nrm =
            sqrtf(v[0] * v[0] + v[1] * v[1] + v[2] * v[2] + v[3] * v[3]);
        const float inv = 1.f / (nrm + 1e-8f);
        ushort4 u;
        u.x = f2h(v[0] * inv); u.y = f2h(v[1] * inv);
        u.z = f2h(v[2] * inv); u.w = f2h(v[3] * inv);
        *(ushort4*)&OutB[(size_t)token * ldout + n] = u;
        if constexpr (EPI == 2) loss += fabsf(v[0] * inv);
      }
    }
    if constexpr (EPI == 2) {
#pragma unroll
      for (int off = 32; off > 0; off >>= 1) loss += __shfl_down(loss, off);
      if (lane == 0) lsum[wave] = loss;
      __syncthreads();
      if (tid == 0)
        atomicAdd(OutF,
                  (lsum[0] + lsum[1] + lsum[2] + lsum[3]) * (1.f / 8388608.f));
    }
  } else {  // EPI == 3 : head
#pragma unroll
    for (int tn = 0; tn < 4; tn++) {
      const int n = nblock + wn + tn * 16 + quad * 4;
      if (n < 257) {
#pragma unroll
        for (int tm = 0; tm < 4; tm++) {
          const int token = mblock + wm + tm * 16 + l15;
          const f32x4 v = acc[tn][tm];
#pragma unroll
          for (int r = 0; r < 4; r++)
            if (n + r < 257) OutF[(size_t)token * 257 + n + r] = v[r];
        }
      }
    }
  }
}

// ---------------------------------------------------------------------------
extern "C" void kernel_launch(void* const* d_in, const int* in_sizes, int n_in,
                              void* d_out, int out_size, void* d_ws,
                              size_t ws_size, hipStream_t stream) {
  const int*   x    = (const int*)d_in[0];
  const float* emb  = (const float*)d_in[1];
  const float* we0  = (const float*)d_in[2];
  const float* we1  = (const float*)d_in[3];
  const float* we2  = (const float*)d_in[4];
  const float* we3  = (const float*)d_in[5];
  const float* we4  = (const float*)d_in[6];
  const float* we5  = (const float*)d_in[7];
  const float* we6  = (const float*)d_in[8];
  const float* we7  = (const float*)d_in[9];
  const float* wlay = (const float*)d_in[10];
  const float* wh   = (const float*)d_in[11];
  float* out = (float*)d_out;

  // workspace layout (~142 MiB)
  char* p = (char*)d_ws;
  auto alloc = [&](size_t bytes) {
    void* r = (void*)p;
    p += (bytes + 255) & ~(size_t)255;
    return r;
  };
  unsigned short* act0 = (unsigned short*)alloc(32768ull * 1024 * 2);
  unsigned short* act1 = (unsigned short*)alloc(32768ull * 1024 * 2);
  unsigned short* E4 = (unsigned short*)alloc(128 * 64 * 2);
  unsigned short* E5 = (unsigned short*)alloc(128 * 128 * 2);
  unsigned short* E6 = (unsigned short*)alloc(256 * 256 * 2);
  unsigned short* E7 = (unsigned short*)alloc(512 * 512 * 2);
  unsigned short* EL = (unsigned short*)alloc(6ull * 1024 * 1024 * 2);
  unsigned short* WH = (unsigned short*)alloc(384 * 1024 * 2);

  // zero the stability-loss slot (d_out is poisoned before every launch)
  hipMemsetAsync(out + 8421376, 0, 4, stream);

  // fused weight prep (all Hamilton expansions + head conversion)
  prep_weights<<<dim3(27488), 256, 0, stream>>>(we4, we5, we6, we7, wlay, wh,
                                                E4, E5, E6, E7, EL, WH);

  // embed + expansion steps 0..3 -> act0 [32768][64] fp16
  embed_expand<<<dim3(128), 256, 0, stream>>>(x, emb, we0, we1, we2, we3, act0);

  // expansion steps 4..7 as fused GEMMs (grid x = n-tiles, y = token-tiles)
  gemm_epi<0><<<dim3(1, 256), 256, 0, stream>>>(E4, act0, act1, nullptr, 64,
                                                64, 128);
  gemm_epi<0><<<dim3(1, 256), 256, 0, stream>>>(E5, act1, act0, nullptr, 128,
                                                128, 256);
  gemm_epi<0><<<dim3(2, 256), 256, 0, stream>>>(E6, act0, act1, nullptr, 256,
                                                256, 512);
  gemm_epi<0><<<dim3(4, 256), 256, 0, stream>>>(E7, act1, act0, nullptr, 512,
                                                512, 1024);

  // 6 quaternion-linear + normalize layers (last also accumulates loss)
  unsigned short* a = act0;
  unsigned short* b = act1;
  for (int d = 0; d < 5; d++) {
    gemm_epi<1><<<dim3(8, 256), 256, 0, stream>>>(EL + (size_t)d * 1048576, a,
                                                  b, nullptr, 1024, 1024, 1024);
    unsigned short* t = a; a = b; b = t;
  }
  gemm_epi<2><<<dim3(8, 256), 256, 0, stream>>>(EL + 5ull * 1048576, a, b,
                                                out + 8421376, 1024, 1024,
                                                1024);
  { unsigned short* t = a; a = b; b = t; }

  // head: logits = h @ w_head^T  (N padded 257 -> 384, masked stores)
  gemm_epi<3><<<dim3(3, 256), 256, 0, stream>>>(WH, a, nullptr, out, 1024, 257,
                                                0);
}